// Round 6
// baseline (575.031 us; speedup 1.0000x reference)
//
#include <hip/hip_runtime.h>
#include <stdint.h>

#define BATCH 4096
#define PLEN  512
#define NSTEP 511
#define FD    64

// ws layout:
//   [0, 2048)                 : colmax bits (512 x u32), init 1.0f, atomicMax'ed
//   [2048, 2048+BATCH*PLEN)   : idx bytes (u8 per (b,t)), t=511 slot written as 0
//   [then, +2MB)              : PH: residual R = conn - I, packed f16.
//                               PH[(k*8+m)*64 + j] = uint4 of f16 rows 8m..8m+7, col j

__global__ void k_init_colmax(unsigned int* cm) {
    int t = threadIdx.x;
    if (t < PLEN) cm[t] = 0x3f800000u; // bits of 1.0f
}

__global__ void k_colmax(const float* __restrict__ bp, unsigned int* __restrict__ cm) {
    __shared__ float red[256];
    int tx = threadIdx.x & 63;
    int ty = threadIdx.x >> 6;
    int t  = blockIdx.x * 64 + tx;            // 0..511
    int b0 = blockIdx.y * 256 + ty * 64;      // 64-row group per wave
    const float* p = bp + (size_t)b0 * PLEN + t;
    float m = 0.0f;
    #pragma unroll 4
    for (int r = 0; r < 64; ++r) {
        m = fmaxf(m, p[(size_t)r * PLEN]);
    }
    red[threadIdx.x] = m;
    __syncthreads();
    if (ty == 0) {
        m = fmaxf(fmaxf(red[tx], red[64 + tx]), fmaxf(red[128 + tx], red[192 + tx]));
        atomicMax((int*)&cm[t], __float_as_int(m)); // values >= 0 -> int-bits monotone
    }
}

__device__ __forceinline__ unsigned short f2h(float x) {
    _Float16 h = (_Float16)x;                 // RNE conversion
    return __builtin_bit_cast(unsigned short, h);
}

// fused: blocks [0,8192) compute idx; blocks [8192,8704) pack the f16 residual
__global__ void k_idx_pack(const float* __restrict__ bp, const unsigned int* __restrict__ cm,
                           uint8_t* __restrict__ idx, const float* __restrict__ conn,
                           uint4* __restrict__ ph) {
    int bid = blockIdx.x;
    if (bid < (BATCH * PLEN) / 256) {
        int gid = bid * 256 + threadIdx.x;    // over BATCH*PLEN
        int t = gid & (PLEN - 1);
        uint8_t k = 0;
        if (t < NSTEP) {
            float mx = __uint_as_float(cm[t]);    // = max(batch max, 1.0)
            float v  = bp[gid];
            float q  = (v * 256.0f) / mx;         // exact reference order
            int ik = (int)q;                      // trunc toward zero (astype int32)
            ik = ik < 0 ? 0 : (ik > 255 ? 255 : ik);
            k = (uint8_t)ik;
        }
        idx[gid] = k;
    } else {
        int gid = (bid - (BATCH * PLEN) / 256) * 256 + threadIdx.x; // over 256*8*64
        int j = gid & 63;
        int m = (gid >> 6) & 7;
        int k = gid >> 9;
        const float* M = conn + ((size_t)k << 12);
        unsigned int w[4];
        #pragma unroll
        for (int d = 0; d < 4; ++d) {
            int i0 = 8 * m + 2 * d, i1 = i0 + 1;
            float x0 = M[i0 * 64 + j] - (i0 == j ? 1.0f : 0.0f); // residual R = M - I
            float x1 = M[i1 * 64 + j] - (i1 == j ? 1.0f : 0.0f);
            w[d] = (unsigned)f2h(x0) | ((unsigned)f2h(x1) << 16);
        }
        ph[gid] = make_uint4(w[0], w[1], w[2], w[3]);
    }
}

// v_fma_mix_f32 with BOTH multiplicands f16:
#define MIX_LL(P, BW, MW) \
    asm("v_fma_mix_f32 %0, %1, %2, %0 op_sel_hi:[1,1,0]" : "+v"(P) : "v"(BW), "v"(MW))
#define MIX_HH(P, BW, MW) \
    asm("v_fma_mix_f32 %0, %1, %2, %0 op_sel:[1,1,0] op_sel_hi:[1,1,0]" : "+v"(P) : "v"(BW), "v"(MW))

// Partial for this wave's 32-row half: q-th matrix word buf[q] pairs with
// broadcast word sv[4*wid+q]. Returns the pure partial (no identity term).
__device__ __forceinline__ float half_partial(float acc, const uint4 buf[4],
                                              unsigned short* sah, int lane, int wid) {
    ((_Float16*)sah)[lane] = (_Float16)acc;            // own-copy f16 bcast (b16 write)
    asm volatile("s_waitcnt lgkmcnt(0)" ::: "memory"); // in-wave visibility
    float p0 = 0.f, p1 = 0.f, p2 = 0.f, p3 = 0.f;
    const uint4* sv = (const uint4*)sah;
    #pragma unroll
    for (int q = 0; q < 4; ++q) {
        uint4 W = sv[4 * wid + q];  // f16 v[ rows 8(4wid+q) .. +7 ] (uniform-addr b128)
        uint4 B = buf[q];           // f16 R rows same range, column `lane`
        MIX_LL(p0, W.x, B.x); MIX_HH(p1, W.x, B.x);
        MIX_LL(p2, W.y, B.y); MIX_HH(p3, W.y, B.y);
        MIX_LL(p0, W.z, B.z); MIX_HH(p1, W.z, B.z);
        MIX_LL(p2, W.w, B.w); MIX_HH(p3, W.w, B.w);
    }
    return (p0 + p1) + (p2 + p3);
}

// 2 waves per chain (row-split), 2 chains per 256-thread block -> 8192 waves,
// 32 waves/CU (vs 16 with 1 wave/chain): doubles outstanding-load depth.
__global__ void __launch_bounds__(256, 8) k_chain(
    const float* __restrict__ fiber, const uint8_t* __restrict__ idx,
    const uint4* __restrict__ ph, float* __restrict__ out)
{
    __shared__ uint32_t sidx32[2][128];                 // 512 idx bytes per chain
    __shared__ __align__(16) unsigned short sah[4][64]; // per-wave f16 bcast copy
    __shared__ float pslot[2][2][2][64];                // [chain][slot][wid][lane]

    int wv   = threadIdx.x >> 6;        // wave in block: 0..3
    int h    = wv >> 1;                 // chain within block
    int wid  = wv & 1;                  // row-half: rows [32*wid, 32*wid+32)
    int lane = threadIdx.x & 63;
    int b    = blockIdx.x * 2 + h;

    sidx32[h][threadIdx.x & 127] =
        ((const uint32_t*)(idx + (size_t)b * PLEN))[threadIdx.x & 127];
    __syncthreads();
    const uint8_t* si = (const uint8_t*)sidx32[h];
    unsigned short* sa = &sah[wv][0];
    float* ps0 = &pslot[h][0][0][0];    // slot 0 base (this chain)
    float* ps1 = &pslot[h][1][0][0];    // slot 1 base

    float acc = fiber[b * FD + lane];   // full v, replicated in both waves

    uint4 bufA[4], bufB[4];
    // row-half base: words m = 4*wid .. 4*wid+3 of each matrix
    const uint4* phw = ph + (size_t)wid * 4 * 64;

    // prologue: load half-matrix for step 0 (compiler-scheduled double buffer)
    int k0 = __builtin_amdgcn_readfirstlane((int)si[0]);
    {
        const uint4* M = phw + ((size_t)k0 << 9);
        #pragma unroll
        for (int m = 0; m < 4; ++m) bufA[m] = M[m * 64 + lane];
    }
    int kn = (int)si[1];

    #pragma unroll 1
    for (int i = 0; i < 255; ++i) {
        // issue loads for step 2i+1
        int kb = __builtin_amdgcn_readfirstlane(kn);
        {
            const uint4* M = phw + ((size_t)kb << 9);
            #pragma unroll
            for (int m = 0; m < 4; ++m) bufB[m] = M[m * 64 + lane];
        }
        int kn2 = (int)si[2 * i + 2];
        // step 2i (slot 0)
        {
            float P = half_partial(acc, bufA, sa, lane, wid);
            ps0[wid * 64 + lane] = P;                   // ds_write_b32
            __syncthreads();
            float other = ps0[(wid ^ 1) * 64 + lane];   // ds_read_b32
            acc = acc + (P + other);  // commutative -> bit-identical in both waves
        }
        // issue loads for step 2i+2
        int ka = __builtin_amdgcn_readfirstlane(kn2);
        {
            const uint4* M = phw + ((size_t)ka << 9);
            #pragma unroll
            for (int m = 0; m < 4; ++m) bufA[m] = M[m * 64 + lane];
        }
        kn = (int)si[2 * i + 3];        // i=254 -> si[511] pad byte (unused)
        // step 2i+1 (slot 1)
        {
            float P = half_partial(acc, bufB, sa, lane, wid);
            ps1[wid * 64 + lane] = P;
            __syncthreads();
            float other = ps1[(wid ^ 1) * 64 + lane];
            acc = acc + (P + other);
        }
    }
    // final step 510 (slot 0)
    {
        float P = half_partial(acc, bufA, sa, lane, wid);
        ps0[wid * 64 + lane] = P;
        __syncthreads();
        float other = ps0[(wid ^ 1) * 64 + lane];
        acc = acc + (P + other);
    }

    if (wid == 0) out[b * FD + lane] = acc;
}

extern "C" void kernel_launch(void* const* d_in, const int* in_sizes, int n_in,
                              void* d_out, int out_size, void* d_ws, size_t ws_size,
                              hipStream_t stream) {
    const float* fiber = (const float*)d_in[0];
    const float* bp    = (const float*)d_in[1];
    const float* conn  = (const float*)d_in[2];
    float* out = (float*)d_out;

    unsigned int* cm = (unsigned int*)d_ws;
    uint8_t* idx = (uint8_t*)d_ws + 2048;
    uint4* ph = (uint4*)((uint8_t*)d_ws + 2048 + (size_t)BATCH * PLEN);

    hipLaunchKernelGGL(k_init_colmax, dim3(1), dim3(512), 0, stream, cm);
    hipLaunchKernelGGL(k_colmax, dim3(8, 16), dim3(256), 0, stream, bp, cm);
    hipLaunchKernelGGL(k_idx_pack, dim3((BATCH * PLEN) / 256 + 512), dim3(256), 0, stream,
                       bp, cm, idx, conn, ph);
    hipLaunchKernelGGL(k_chain, dim3(BATCH / 2), dim3(256), 0, stream, fiber, idx, ph, out);
}

// Round 7
// 526.048 us; speedup vs baseline: 1.0931x; 1.0931x over previous
//
#include <hip/hip_runtime.h>
#include <stdint.h>

#define BATCH 4096
#define PLEN  512
#define NSTEP 511
#define FD    64

// ws layout:
//   [0, 2048)                 : colmax bits (512 x u32), init 1.0f, atomicMax'ed
//   [2048, 2048+BATCH*PLEN)   : idx bytes (u8 per (b,t)), t=511 slot written as 0
//   [then, +2MB)              : PH: residual R = conn - I, packed f16.
//                               PH[(k*8+m)*64 + j] = uint4 of f16 rows 8m..8m+7, col j
//
// Roofline note (R4/R5/R6 triangulation): the chain kernel is pinned at
// ~47.6 B/cyc/CU of random matrix-gather from L2 (83% of the measured L2
// ceiling incl. L1 assist). Forced deeper prefetch (R4: -4%) and 2x occupancy
// via row-split (R6: -8%) both regress; compiler-scheduled double-buffer with
// 1 wave/chain (this version) is the best-measured schedule. f16 residual is
// the minimal numerically-safe encoding (int8/fp8 walk-error exceeds the
// 2.7 absmax threshold).

__global__ void k_init_colmax(unsigned int* cm) {
    int t = threadIdx.x;
    if (t < PLEN) cm[t] = 0x3f800000u; // bits of 1.0f
}

__global__ void k_colmax(const float* __restrict__ bp, unsigned int* __restrict__ cm) {
    __shared__ float red[256];
    int tx = threadIdx.x & 63;
    int ty = threadIdx.x >> 6;
    int t  = blockIdx.x * 64 + tx;            // 0..511
    int b0 = blockIdx.y * 256 + ty * 64;      // 64-row group per wave
    const float* p = bp + (size_t)b0 * PLEN + t;
    float m = 0.0f;
    #pragma unroll 4
    for (int r = 0; r < 64; ++r) {
        m = fmaxf(m, p[(size_t)r * PLEN]);
    }
    red[threadIdx.x] = m;
    __syncthreads();
    if (ty == 0) {
        m = fmaxf(fmaxf(red[tx], red[64 + tx]), fmaxf(red[128 + tx], red[192 + tx]));
        atomicMax((int*)&cm[t], __float_as_int(m)); // values >= 0 -> int-bits monotone
    }
}

__device__ __forceinline__ unsigned short f2h(float x) {
    _Float16 h = (_Float16)x;                 // RNE conversion
    return __builtin_bit_cast(unsigned short, h);
}

// fused: blocks [0,8192) compute idx; blocks [8192,8704) pack the f16 residual
__global__ void k_idx_pack(const float* __restrict__ bp, const unsigned int* __restrict__ cm,
                           uint8_t* __restrict__ idx, const float* __restrict__ conn,
                           uint4* __restrict__ ph) {
    int bid = blockIdx.x;
    if (bid < (BATCH * PLEN) / 256) {
        int gid = bid * 256 + threadIdx.x;    // over BATCH*PLEN
        int t = gid & (PLEN - 1);
        uint8_t k = 0;
        if (t < NSTEP) {
            float mx = __uint_as_float(cm[t]);    // = max(batch max, 1.0)
            float v  = bp[gid];
            float q  = (v * 256.0f) / mx;         // exact reference order
            int ik = (int)q;                      // trunc toward zero (astype int32)
            ik = ik < 0 ? 0 : (ik > 255 ? 255 : ik);
            k = (uint8_t)ik;
        }
        idx[gid] = k;
    } else {
        int gid = (bid - (BATCH * PLEN) / 256) * 256 + threadIdx.x; // over 256*8*64
        int j = gid & 63;
        int m = (gid >> 6) & 7;
        int k = gid >> 9;
        const float* M = conn + ((size_t)k << 12);
        unsigned int w[4];
        #pragma unroll
        for (int d = 0; d < 4; ++d) {
            int i0 = 8 * m + 2 * d, i1 = i0 + 1;
            float x0 = M[i0 * 64 + j] - (i0 == j ? 1.0f : 0.0f); // residual R = M - I
            float x1 = M[i1 * 64 + j] - (i1 == j ? 1.0f : 0.0f);
            w[d] = (unsigned)f2h(x0) | ((unsigned)f2h(x1) << 16);
        }
        ph[gid] = make_uint4(w[0], w[1], w[2], w[3]);
    }
}

// v_fma_mix_f32 with BOTH multiplicands f16 (op_sel_hi[0]=op_sel_hi[1]=1):
//   LL: take lo halves of broadcast word BW and matrix word MW
//   HH: take hi halves of both
#define MIX_LL(P, BW, MW) \
    asm("v_fma_mix_f32 %0, %1, %2, %0 op_sel_hi:[1,1,0]" : "+v"(P) : "v"(BW), "v"(MW))
#define MIX_HH(P, BW, MW) \
    asm("v_fma_mix_f32 %0, %1, %2, %0 op_sel:[1,1,0] op_sel_hi:[1,1,0]" : "+v"(P) : "v"(BW), "v"(MW))

// One chain step: v' = v + v*R, R in f16 (buf), broadcast of v in f16 via LDS.
// State acc stays f32 (identity term carried in full precision by p0 = acc).
__device__ __forceinline__ float step16h(float acc, const uint4 buf[8],
                                         unsigned short* sah, int lane) {
    ((_Float16*)sah)[lane] = (_Float16)acc;            // v_cvt_f16_f32 + ds_write_b16
    asm volatile("s_waitcnt lgkmcnt(0)" ::: "memory"); // cross-lane visibility in-wave
    float p0 = acc, p1 = 0.f, p2 = 0.f, p3 = 0.f;      // p0 carries the identity term
    const uint4* sv = (const uint4*)sah;               // 8 b128 words = 64 f16 broadcasts
    #pragma unroll
    for (int q = 0; q < 8; ++q) {
        uint4 B = buf[q];     // f16 rows 8q..8q+7 of column `lane` (pairs in .x..)
        uint4 W = sv[q];      // f16 v[8q..8q+7] (pairs in .x..)
        MIX_LL(p0, W.x, B.x); MIX_HH(p1, W.x, B.x);
        MIX_LL(p2, W.y, B.y); MIX_HH(p3, W.y, B.y);
        MIX_LL(p0, W.z, B.z); MIX_HH(p1, W.z, B.z);
        MIX_LL(p2, W.w, B.w); MIX_HH(p3, W.w, B.w);
    }
    return (p0 + p1) + (p2 + p3);
}

__global__ void __launch_bounds__(256) k_chain(
    const float* __restrict__ fiber, const uint8_t* __restrict__ idx,
    const uint4* __restrict__ ph, float* __restrict__ out)
{
    __shared__ uint64_t sidx64[4][64];                 // 512 idx bytes per wave's chain
    __shared__ __align__(16) unsigned short sah[4][64]; // per-wave f16 broadcast buffer
    int wid  = threadIdx.x >> 6;
    int lane = threadIdx.x & 63;
    int b = blockIdx.x * 4 + wid;

    sidx64[wid][lane] = ((const uint64_t*)(idx + (size_t)b * PLEN))[lane];
    __syncthreads();
    const uint8_t* si = (const uint8_t*)sidx64[wid];
    unsigned short* sa = &sah[wid][0];

    float acc = fiber[b * FD + lane];    // lane j holds v[j]

    uint4 bufA[8], bufB[8];

    // prologue: load residual for step 0 (compiler-scheduled double buffer —
    // R4 showed forced asm prefetch + sched fences is slower than this)
    int k0 = __builtin_amdgcn_readfirstlane((int)si[0]);
    {
        const uint4* M = ph + ((size_t)k0 << 9);
        #pragma unroll
        for (int m = 0; m < 8; ++m) bufA[m] = M[m * 64 + lane];
    }
    int kn = (int)si[1];

    #pragma unroll 1
    for (int i = 0; i < 255; ++i) {
        // issue loads for step 2i+1
        int kb = __builtin_amdgcn_readfirstlane(kn);
        {
            const uint4* M = ph + ((size_t)kb << 9);
            #pragma unroll
            for (int m = 0; m < 8; ++m) bufB[m] = M[m * 64 + lane];
        }
        int kn2 = (int)si[2 * i + 2];
        acc = step16h(acc, bufA, sa, lane);     // compute step 2i
        // issue loads for step 2i+2
        int ka = __builtin_amdgcn_readfirstlane(kn2);
        {
            const uint4* M = ph + ((size_t)ka << 9);
            #pragma unroll
            for (int m = 0; m < 8; ++m) bufA[m] = M[m * 64 + lane];
        }
        kn = (int)si[2 * i + 3];                // i=254 -> si[511] pad byte (unused)
        acc = step16h(acc, bufB, sa, lane);     // compute step 2i+1
    }
    acc = step16h(acc, bufA, sa, lane);         // final step 510

    out[b * FD + lane] = acc;
}

extern "C" void kernel_launch(void* const* d_in, const int* in_sizes, int n_in,
                              void* d_out, int out_size, void* d_ws, size_t ws_size,
                              hipStream_t stream) {
    const float* fiber = (const float*)d_in[0];
    const float* bp    = (const float*)d_in[1];
    const float* conn  = (const float*)d_in[2];
    float* out = (float*)d_out;

    unsigned int* cm = (unsigned int*)d_ws;
    uint8_t* idx = (uint8_t*)d_ws + 2048;
    uint4* ph = (uint4*)((uint8_t*)d_ws + 2048 + (size_t)BATCH * PLEN);

    hipLaunchKernelGGL(k_init_colmax, dim3(1), dim3(512), 0, stream, cm);
    hipLaunchKernelGGL(k_colmax, dim3(8, 16), dim3(256), 0, stream, bp, cm);
    hipLaunchKernelGGL(k_idx_pack, dim3((BATCH * PLEN) / 256 + 512), dim3(256), 0, stream,
                       bp, cm, idx, conn, ph);
    hipLaunchKernelGGL(k_chain, dim3(BATCH / 4), dim3(256), 0, stream, fiber, idx, ph, out);
}